// Round 9
// baseline (110.608 us; speedup 1.0000x reference)
//
#include <hip/hip_runtime.h>
#include <math.h>

#define NV 20
#define NC 64
#define NSTATES (1u << 20)
#define TOPK 10
#define NB1 256              // ptop blocks
#define NCAND (NB1 * TOPK)   // 2560

// ===========================================================================
// Walsh-Hadamard pipeline. Index j (20 bits) = [row r: bits 12..19][col l:
// bits 0..11]. Wr = WHT-12 within each contiguous 4096-block (one block per
// row, 1024 threads, quad-per-thread). Wc = WHT-8 across rows (blocks own
// 16-column slices). Mixer_L = Wr Wc [(1+s_L*(20-2popc))/2^20] Wc Wr.
// Chain (normalization fully deferred to the end):
//   K1: costs + x0=2^-10*cos(g0*c) + Wr          -> A
//   K2: Wc ((1+s0*Lam)/256) Wc                   (in-place A)
//   K3: Wr, *2^-12, *cos(g1*c), Wr               (in-place A)
//   K4: Wc-mid (s1)   K5: row-mid (g2)   K6: Wc-mid (s2)
//   K7: Wr, *2^-12 -> m2 -> B, sumsq -> scal[0]
//   K8: probs = (m2/sqrt(scal))^2 + top-k + readout
// ===========================================================================

// in-register WHT over quad bits 0,1
__device__ __forceinline__ float4 wht4(float4 v) {
  float a0 = v.x + v.y, a1 = v.x - v.y, a2 = v.z + v.w, a3 = v.z - v.w;
  float4 r;
  r.x = a0 + a2; r.y = a1 + a3; r.z = a0 - a2; r.w = a1 - a3;
  return r;
}

// WHT over quad-index bits 0..9 (element bits 2..11): 10 LDS exchange stages,
// alternating buffers, one __syncthreads per stage.
__device__ __forceinline__ float4 wht_lds10(float4 v, int tid,
                                            float4* b0, float4* b1, int& sel) {
  #pragma unroll
  for (int st = 0; st < 10; ++st) {
    float4* b = sel ? b1 : b0; sel ^= 1;
    b[tid] = v;
    __syncthreads();
    float4 p = b[tid ^ (1 << st)];
    if (((tid >> st) & 1) == 0) {
      v.x += p.x; v.y += p.y; v.z += p.z; v.w += p.w;
    } else {
      v.x = p.x - v.x; v.y = p.y - v.y; v.z = p.z - v.z; v.w = p.w - v.w;
    }
  }
  return v;
}

// ---------------------------------------------------------------------------
// K1: costs (chunked, validated numerics) + x0 + Wr. Also zeroes scal/ctr.
// ---------------------------------------------------------------------------
__global__ __launch_bounds__(1024) void k_costs_wht(const float* __restrict__ C,
                                                    float* __restrict__ costs,
                                                    float* __restrict__ A,
                                                    const float* __restrict__ gamma,
                                                    double* __restrict__ scal,
                                                    unsigned* __restrict__ ctr) {
  __shared__ float CT[17][NC];
  __shared__ float lowT[8][NC];
  __shared__ float4 rb0[1024], rb1[1024];
  const int tid = threadIdx.x;
  const unsigned t = blockIdx.x * 1024u + (unsigned)tid;  // quad index < 2^18

  if (blockIdx.x == 0) {
    if (tid < 8) scal[tid] = 0.0;
    if (tid == 8) *ctr = 0u;
  }

  for (int e = tid; e < 17 * NC; e += 1024) {
    int k = e / NC, c = e % NC;
    CT[k][c] = C[c * NV + (16 - k)];
  }
  for (int e = tid; e < 8 * NC; e += 1024) {
    int m = e >> 6, c = e & 63;
    float v = 0.0f;
    if (m & 1) v += C[c * NV + 19];
    if (m & 2) v += C[c * NV + 18];
    if (m & 4) v += C[c * NV + 17];
    lowT[m][c] = v;
  }
  __syncthreads();

  float cost[4];
  #pragma unroll
  for (int s = 0; s < 4; ++s)
    cost[s] = 0.1f * (float)__popc(4u * t + (unsigned)s);
  const int m01 = (int)((t & 1u) << 2);

  #pragma unroll
  for (int cc = 0; cc < 4; ++cc) {       // 16 constraints per chunk
    float4 bb[4];
    #pragma unroll
    for (int q = 0; q < 4; ++q) bb[q] = make_float4(-1.f, -1.f, -1.f, -1.f);
    #pragma unroll
    for (int k = 0; k < 17; ++k) {       // i-bit (k+3) == t-bit (k+1)
      float bf = (float)((t >> (k + 1)) & 1u);
      const float4* row = ((const float4*)(&CT[k][0])) + 4 * cc;
      #pragma unroll
      for (int q = 0; q < 4; ++q) {
        float4 cv = row[q];
        bb[q].x = fmaf(bf, cv.x, bb[q].x);
        bb[q].y = fmaf(bf, cv.y, bb[q].y);
        bb[q].z = fmaf(bf, cv.z, bb[q].z);
        bb[q].w = fmaf(bf, cv.w, bb[q].w);
      }
    }
    #pragma unroll
    for (int s = 0; s < 4; ++s) {
      const float4* lrow = ((const float4*)(&lowT[m01 | s][0])) + 4 * cc;
      #pragma unroll
      for (int q = 0; q < 4; ++q) {
        float4 lv = lrow[q];
        float4 v;
        v.x = bb[q].x + lv.x; v.y = bb[q].y + lv.y;
        v.z = bb[q].z + lv.z; v.w = bb[q].w + lv.w;
        float r;
        r = fmaxf(v.x, 0.f); cost[s] = fmaf(r, r, cost[s]);
        r = fmaxf(v.y, 0.f); cost[s] = fmaf(r, r, cost[s]);
        r = fmaxf(v.z, 0.f); cost[s] = fmaf(r, r, cost[s]);
        r = fmaxf(v.w, 0.f); cost[s] = fmaf(r, r, cost[s]);
      }
    }
  }

  ((float4*)costs)[t] = make_float4(cost[0], cost[1], cost[2], cost[3]);

  float g0 = gamma[0];
  float4 v;
  v.x = 0x1p-10f * cosf(g0 * cost[0]);
  v.y = 0x1p-10f * cosf(g0 * cost[1]);
  v.z = 0x1p-10f * cosf(g0 * cost[2]);
  v.w = 0x1p-10f * cosf(g0 * cost[3]);

  v = wht4(v);
  int sel = 0;
  v = wht_lds10(v, tid, rb0, rb1, sel);
  ((float4*)A)[t] = v;
}

// ---------------------------------------------------------------------------
// K2/K4/K6: column pass, in-place on A.  Wc (1+s*Lam)/256 Wc over the high
// 8 bits (rows), per 16-column slice. Padded word tile [256][17] x2 buffers.
// ---------------------------------------------------------------------------
__global__ __launch_bounds__(1024) void k_col(float* __restrict__ A,
                                              const float* __restrict__ beta,
                                              int layer) {
  __shared__ float w0[256 * 17];
  __shared__ float w1[256 * 17];
  const int tid = threadIdx.x;
  const unsigned c0 = blockIdx.x * 16u;        // base column (low-12 value)
  const float s = 0.1f * sinf(beta[layer]);

  // load: thread (lr, cq) owns float4 = cols cq*4..+3 of row lr
  const int lr = tid >> 2, cq = tid & 3;
  const size_t gq = (size_t)lr * 1024 + (c0 >> 2) + (unsigned)cq;
  float4 v4 = ((const float4*)A)[gq];
  w0[lr * 17 + cq * 4 + 0] = v4.x;
  w0[lr * 17 + cq * 4 + 1] = v4.y;
  w0[lr * 17 + cq * 4 + 2] = v4.z;
  w0[lr * 17 + cq * 4 + 3] = v4.w;
  __syncthreads();

  // compute ownership: rows br+64k (k=0..3), column col
  const int br = tid >> 4, col = tid & 15;
  float v[4];
  #pragma unroll
  for (int k = 0; k < 4; ++k) v[k] = w0[(br + 64 * k) * 17 + col];
  int sel = 1;                                  // next write -> w1

  // forward LDS stages: row bits 0..5
  #pragma unroll
  for (int st = 0; st < 6; ++st) {
    float* b = sel ? w1 : w0; sel ^= 1;
    #pragma unroll
    for (int k = 0; k < 4; ++k) b[(br + 64 * k) * 17 + col] = v[k];
    __syncthreads();
    float p[4];
    #pragma unroll
    for (int k = 0; k < 4; ++k) p[k] = b[((br ^ (1 << st)) + 64 * k) * 17 + col];
    if (((br >> st) & 1) == 0) {
      #pragma unroll
      for (int k = 0; k < 4; ++k) v[k] += p[k];
    } else {
      #pragma unroll
      for (int k = 0; k < 4; ++k) v[k] = p[k] - v[k];
    }
  }
  // register stages: row bits 6,7 (across k)
  {
    float n0 = v[0] + v[1], n1 = v[0] - v[1], n2 = v[2] + v[3], n3 = v[2] - v[3];
    v[0] = n0 + n2; v[1] = n1 + n3; v[2] = n0 - n2; v[3] = n1 - n3;
  }
  // middle: multiply by (1 + s*(20-2*popc(j)))/256
  const int popl = __popc(c0 | (unsigned)col);
  #pragma unroll
  for (int k = 0; k < 4; ++k) {
    int lam = 20 - 2 * (__popc((unsigned)(br + 64 * k)) + popl);
    v[k] *= (1.0f + s * (float)lam) * 0x1p-8f;
  }
  // inverse: register stages, then LDS stages (all stages commute)
  {
    float n0 = v[0] + v[1], n1 = v[0] - v[1], n2 = v[2] + v[3], n3 = v[2] - v[3];
    v[0] = n0 + n2; v[1] = n1 + n3; v[2] = n0 - n2; v[3] = n1 - n3;
  }
  #pragma unroll
  for (int st = 0; st < 6; ++st) {
    float* b = sel ? w1 : w0; sel ^= 1;
    #pragma unroll
    for (int k = 0; k < 4; ++k) b[(br + 64 * k) * 17 + col] = v[k];
    __syncthreads();
    float p[4];
    #pragma unroll
    for (int k = 0; k < 4; ++k) p[k] = b[((br ^ (1 << st)) + 64 * k) * 17 + col];
    if (((br >> st) & 1) == 0) {
      #pragma unroll
      for (int k = 0; k < 4; ++k) v[k] += p[k];
    } else {
      #pragma unroll
      for (int k = 0; k < 4; ++k) v[k] = p[k] - v[k];
    }
  }
  // writeback via reorg
  {
    float* b = sel ? w1 : w0;
    #pragma unroll
    for (int k = 0; k < 4; ++k) b[(br + 64 * k) * 17 + col] = v[k];
    __syncthreads();
    float4 o;
    o.x = b[lr * 17 + cq * 4 + 0];
    o.y = b[lr * 17 + cq * 4 + 1];
    o.z = b[lr * 17 + cq * 4 + 2];
    o.w = b[lr * 17 + cq * 4 + 3];
    ((float4*)A)[gq] = o;
  }
}

// ---------------------------------------------------------------------------
// K3/K5: row pass, in-place: Wr, *2^-12, *cos(gamma[gi]*cost), Wr
// ---------------------------------------------------------------------------
__global__ __launch_bounds__(1024) void k_row_mid(float* __restrict__ A,
                                                  const float* __restrict__ costs,
                                                  const float* __restrict__ gamma,
                                                  int gi) {
  __shared__ float4 rb0[1024], rb1[1024];
  const int tid = threadIdx.x;
  const size_t q = (size_t)blockIdx.x * 1024 + tid;
  float4 v = ((const float4*)A)[q];
  int sel = 0;
  v = wht4(v);
  v = wht_lds10(v, tid, rb0, rb1, sel);
  const float g = gamma[gi];
  float4 c = ((const float4*)costs)[q];
  v.x = v.x * 0x1p-12f * cosf(g * c.x);
  v.y = v.y * 0x1p-12f * cosf(g * c.y);
  v.z = v.z * 0x1p-12f * cosf(g * c.z);
  v.w = v.w * 0x1p-12f * cosf(g * c.w);
  v = wht4(v);
  v = wht_lds10(v, tid, rb0, rb1, sel);
  ((float4*)A)[q] = v;
}

// ---------------------------------------------------------------------------
// K7: final row pass: Wr, *2^-12 -> m2 -> B; sumsq -> scal[0]
// ---------------------------------------------------------------------------
template <bool AL>
__global__ __launch_bounds__(1024) void k_row_fin(const float* __restrict__ A,
                                                  float* __restrict__ B,
                                                  double* __restrict__ scal) {
  __shared__ float4 rb0[1024], rb1[1024];
  __shared__ double dpart[16];
  const int tid = threadIdx.x;
  const size_t q = (size_t)blockIdx.x * 1024 + tid;
  float4 v = ((const float4*)A)[q];
  int sel = 0;
  v = wht4(v);
  v = wht_lds10(v, tid, rb0, rb1, sel);
  v.x *= 0x1p-12f; v.y *= 0x1p-12f; v.z *= 0x1p-12f; v.w *= 0x1p-12f;

  if (AL) {
    ((float4*)B)[q] = v;
  } else {
    B[4 * q + 0] = v.x; B[4 * q + 1] = v.y;
    B[4 * q + 2] = v.z; B[4 * q + 3] = v.w;
  }

  double ss = (double)v.x * v.x + (double)v.y * v.y +
              (double)v.z * v.z + (double)v.w * v.w;
  #pragma unroll
  for (int off = 32; off > 0; off >>= 1) ss += __shfl_down(ss, off);
  if ((tid & 63) == 0) dpart[tid >> 6] = ss;
  __syncthreads();
  if (tid == 0) {
    double tt = 0.0;
    #pragma unroll
    for (int w = 0; w < 16; ++w) tt += dpart[w];
    atomicAdd(&scal[0], tt);
  }
}

// ---------------------------------------------------------------------------
// K8: fused probs + top-k stage 1 + (last block) merge & readout (R8 code).
// ---------------------------------------------------------------------------
template <bool ALIN>
__global__ __launch_bounds__(256) void k_ptop(const float* __restrict__ A,
                                              const double* __restrict__ scal2,
                                              const float* __restrict__ costs,
                                              float* __restrict__ out,
                                              unsigned long long* __restrict__ cand,
                                              unsigned* __restrict__ ctr) {
    __shared__ unsigned long long warr[4];
    __shared__ int lastblk;
    __shared__ unsigned topi[TOPK];
    __shared__ float topc[TOPK];
    const int tid = threadIdx.x;
    float* probs_out = out + 21;
    unsigned b4 = blockIdx.x * 1024u;
    float scale = (float)(1.0 / sqrt(*scal2));

    unsigned long long k[16];
    #pragma unroll
    for (int u = 0; u < 4; ++u) {
        unsigned j4 = b4 + (unsigned)tid + 256u * u;
        float4 v;
        if (ALIN) v = ((const float4*)A)[j4];
        else {
            v.x = A[4u * j4 + 0]; v.y = A[4u * j4 + 1];
            v.z = A[4u * j4 + 2]; v.w = A[4u * j4 + 3];
        }
        float4 p;
        p.x = v.x * scale; p.x *= p.x;
        p.y = v.y * scale; p.y *= p.y;
        p.z = v.z * scale; p.z *= p.z;
        p.w = v.w * scale; p.w *= p.w;
        unsigned e0 = 4u * j4;
        probs_out[e0 + 0] = p.x; probs_out[e0 + 1] = p.y;
        probs_out[e0 + 2] = p.z; probs_out[e0 + 3] = p.w;
        k[4 * u + 0] = ((unsigned long long)__float_as_uint(p.x) << 32) | (unsigned long long)(0xFFFFFFFFu - (e0 + 0));
        k[4 * u + 1] = ((unsigned long long)__float_as_uint(p.y) << 32) | (unsigned long long)(0xFFFFFFFFu - (e0 + 1));
        k[4 * u + 2] = ((unsigned long long)__float_as_uint(p.z) << 32) | (unsigned long long)(0xFFFFFFFFu - (e0 + 2));
        k[4 * u + 3] = ((unsigned long long)__float_as_uint(p.w) << 32) | (unsigned long long)(0xFFFFFFFFu - (e0 + 3));
    }

    for (int r = 0; r < TOPK; ++r) {
        unsigned long long loc = 0ull;
        #pragma unroll
        for (int j = 0; j < 16; ++j) if (k[j] > loc) loc = k[j];
        #pragma unroll
        for (int off = 32; off > 0; off >>= 1) {
            unsigned long long o = __shfl_down(loc, off);
            if (o > loc) loc = o;
        }
        if ((tid & 63) == 0) warr[tid >> 6] = loc;
        __syncthreads();
        unsigned long long win = warr[0];
        if (warr[1] > win) win = warr[1];
        if (warr[2] > win) win = warr[2];
        if (warr[3] > win) win = warr[3];
        __syncthreads();
        #pragma unroll
        for (int j = 0; j < 16; ++j) if (k[j] == win) k[j] = 0ull;
        if (tid == 0) cand[blockIdx.x * TOPK + r] = win;
    }

    __threadfence();
    if (tid == 0) {
        unsigned old = atomicAdd(ctr, 1u);
        lastblk = (old == NB1 - 1) ? 1 : 0;
    }
    __syncthreads();
    if (!lastblk) return;
    __threadfence();

    unsigned long long c2[TOPK];
    #pragma unroll
    for (int u = 0; u < TOPK; ++u) c2[u] = cand[tid + 256 * u];

    for (int r = 0; r < TOPK; ++r) {
        unsigned long long loc = 0ull;
        #pragma unroll
        for (int u = 0; u < TOPK; ++u) if (c2[u] > loc) loc = c2[u];
        #pragma unroll
        for (int off = 32; off > 0; off >>= 1) {
            unsigned long long o = __shfl_down(loc, off);
            if (o > loc) loc = o;
        }
        if ((tid & 63) == 0) warr[tid >> 6] = loc;
        __syncthreads();
        unsigned long long win = warr[0];
        if (warr[1] > win) win = warr[1];
        if (warr[2] > win) win = warr[2];
        if (warr[3] > win) win = warr[3];
        __syncthreads();
        #pragma unroll
        for (int u = 0; u < TOPK; ++u) if (c2[u] == win) c2[u] = 0ull;
        if (tid == 0) topi[r] = 0xFFFFFFFFu - (unsigned)(win & 0xFFFFFFFFull);
        __syncthreads();
    }

    const unsigned S = NSTATES;
    if (tid < TOPK * NV) {
        int kk = tid / NV, vv = tid % NV;
        out[21 + S + (unsigned)tid] = (float)((topi[kk] >> (NV - 1 - vv)) & 1u);
    }
    if (tid < TOPK) {
        float c = costs[topi[tid]];
        topc[tid] = c;
        out[21 + S + TOPK * NV + (unsigned)tid] = c;
    }
    __syncthreads();
    if (tid == 0) {
        int best = 0;
        for (int kk = 1; kk < TOPK; ++kk)
            if (topc[kk] < topc[best]) best = kk;
        unsigned gi = topi[best];
        for (int vv = 0; vv < NV; ++vv)
            out[vv] = (float)((gi >> (NV - 1 - vv)) & 1u);
        out[NV] = topc[best];
    }
}

extern "C" void kernel_launch(void* const* d_in, const int* in_sizes, int n_in,
                              void* d_out_, int out_size, void* d_ws, size_t ws_size,
                              hipStream_t stream) {
    (void)in_sizes; (void)n_in; (void)out_size;
    const float* C     = (const float*)d_in[0];
    const float* beta  = (const float*)d_in[1];
    const float* gamma = (const float*)d_in[2];
    float* out = (float*)d_out_;
    char* ws = (char*)d_ws;
    const size_t S4 = (size_t)NSTATES * sizeof(float);

    double* scal = (double*)ws;                                   // 8 doubles
    unsigned* ctr = (unsigned*)(ws + 64);
    unsigned long long* cand = (unsigned long long*)(ws + 1024);  // 20 KB
    float* costs = (float*)(ws + 32768);
    float* A     = (float*)(ws + 32768 + S4);
    const size_t need_full = 32768 + 3 * S4;
    bool wsbig = (ws_size >= need_full);
    float* B = wsbig ? (float*)(ws + 32768 + 2 * S4) : (out + 21);

    k_costs_wht<<<256, 1024, 0, stream>>>(C, costs, A, gamma, scal, ctr);
    k_col     <<<256, 1024, 0, stream>>>(A, beta, 0);
    k_row_mid <<<256, 1024, 0, stream>>>(A, costs, gamma, 1);
    k_col     <<<256, 1024, 0, stream>>>(A, beta, 1);
    k_row_mid <<<256, 1024, 0, stream>>>(A, costs, gamma, 2);
    k_col     <<<256, 1024, 0, stream>>>(A, beta, 2);
    if (wsbig) {
        k_row_fin<true ><<<256, 1024, 0, stream>>>(A, B, scal);
        k_ptop<true ><<<NB1, 256, 0, stream>>>(B, scal, costs, out, cand, ctr);
    } else {
        k_row_fin<false><<<256, 1024, 0, stream>>>(A, B, scal);
        k_ptop<false><<<NB1, 256, 0, stream>>>(B, scal, costs, out, cand, ctr);
    }
}

// Round 10
// 89.553 us; speedup vs baseline: 1.2351x; 1.2351x over previous
//
#include <hip/hip_runtime.h>
#include <math.h>

#define NV 20
#define NC 64
#define NSTATES (1u << 20)
#define TOPK 10
#define NB1 256              // ptop blocks
#define NCAND (NB1 * TOPK)   // 2560

// XCD-locality swizzle: blocks with equal (blockIdx&7) share an XCD under the
// hardware's round-robin mapping; give each XCD a contiguous group of 32
// data-blocks so XOR-gathers at data-block bits 0..4 stay XCD-local.
__device__ __forceinline__ unsigned dbswz(unsigned x) {
    return ((x & 7u) << 5) | (x >> 3);
}

// ---------------------------------------------------------------------------
// costs[i] = sum_c relu(bits(i)·C_c - 1)^2 + 0.1*popcount(i)
// Also emits ph0[i] = 2^-10*cos(gamma0*costs[i]); zeroes scal/ctr.
// 256 blocks x 512 threads, 8 states/thread; block handles data-block
// dbswz(blockIdx) (same ownership as the mixers -> producer/consumer L2
// alignment). Chunked constraint accumulation, c ascending — bitwise
// identical numerics to the validated R4/R8 kernels (absmax 2.98e-8).
// ---------------------------------------------------------------------------
__global__ __launch_bounds__(512) void k_costs(const float* __restrict__ C,
                                               float* __restrict__ costs,
                                               float* __restrict__ ph0,
                                               const float* __restrict__ gamma,
                                               double* __restrict__ scal,
                                               unsigned* __restrict__ ctr) {
    __shared__ float CT[17][NC];    // CT[k][c] = C[c][16-k]
    __shared__ float lowT[8][NC];   // low 3 bits (cols 19,18,17)
    const int tid = threadIdx.x;

    if (blockIdx.x == 0) {
        if (tid < 8) scal[tid] = 0.0;
        if (tid == 8) *ctr = 0u;
    }

    for (int e = tid; e < 17 * NC; e += 512) {
        int k = e / NC, c = e % NC;
        CT[k][c] = C[c * NV + (16 - k)];
    }
    for (int e = tid; e < 8 * NC; e += 512) {
        int m = e >> 6, c = e & 63;
        float v = 0.0f;
        if (m & 1) v += C[c * NV + 19];
        if (m & 2) v += C[c * NV + 18];
        if (m & 4) v += C[c * NV + 17];
        lowT[m][c] = v;
    }
    __syncthreads();

    const unsigned db = dbswz(blockIdx.x);
    unsigned t = db * 512u + (unsigned)tid;   // < 2^17, 8 states each
    float g0 = gamma[0];

    float cost[8];
    #pragma unroll
    for (int s = 0; s < 8; ++s)
        cost[s] = 0.1f * (float)__popc(t * 8u + (unsigned)s);

    #pragma unroll
    for (int cc = 0; cc < 4; ++cc) {       // 16 constraints per chunk
        float4 bb[4];
        #pragma unroll
        for (int q = 0; q < 4; ++q) bb[q] = make_float4(-1.f, -1.f, -1.f, -1.f);
        #pragma unroll
        for (int k = 0; k < 17; ++k) {     // i-bit (k+3) == t-bit k
            float bf = (float)((t >> k) & 1u);
            const float4* row = ((const float4*)(&CT[k][0])) + 4 * cc;
            #pragma unroll
            for (int q = 0; q < 4; ++q) {
                float4 cv = row[q];
                bb[q].x = fmaf(bf, cv.x, bb[q].x);
                bb[q].y = fmaf(bf, cv.y, bb[q].y);
                bb[q].z = fmaf(bf, cv.z, bb[q].z);
                bb[q].w = fmaf(bf, cv.w, bb[q].w);
            }
        }
        #pragma unroll
        for (int s = 0; s < 8; ++s) {
            const float4* lrow = ((const float4*)(&lowT[s][0])) + 4 * cc;
            #pragma unroll
            for (int q = 0; q < 4; ++q) {
                float4 lv = lrow[q];
                float4 v;
                v.x = bb[q].x + lv.x; v.y = bb[q].y + lv.y;
                v.z = bb[q].z + lv.z; v.w = bb[q].w + lv.w;
                float r;
                r = fmaxf(v.x, 0.f); cost[s] = fmaf(r, r, cost[s]);
                r = fmaxf(v.y, 0.f); cost[s] = fmaf(r, r, cost[s]);
                r = fmaxf(v.z, 0.f); cost[s] = fmaf(r, r, cost[s]);
                r = fmaxf(v.w, 0.f); cost[s] = fmaf(r, r, cost[s]);
            }
        }
    }

    float4* co = (float4*)(costs + (size_t)t * 8u);
    co[0] = make_float4(cost[0], cost[1], cost[2], cost[3]);
    co[1] = make_float4(cost[4], cost[5], cost[6], cost[7]);
    float ph[8];
    #pragma unroll
    for (int s = 0; s < 8; ++s) ph[s] = 0x1p-10f * cosf(g0 * cost[s]);
    float4* po = (float4*)(ph0 + (size_t)t * 8u);
    po[0] = make_float4(ph[0], ph[1], ph[2], ph[3]);
    po[1] = make_float4(ph[4], ph[5], ph[6], ph[7]);
}

// ---------------------------------------------------------------------------
// LDS-tiled mixer over pre-phased pin (validated R4 structure, 8-wide gather
// batch restored). Block owns data-block dbswz(blockIdx): far gathers at
// data-block bits 0..4 (p=12..16) are then XCD-local L2 hits; only p=17..19
// cross XCDs. Summation order (g19..g12, t11..t2, own^2, own^1) unchanged ->
// bitwise identical to R4.
//   m[i]  = prevscale * (pin[i] + s*sum_{p=19..0} pin[i^(1<<p)])
//   LAYER<2: pout = m*cos(gamma[L+1]*costs);  LAYER==2: pout = m
// ---------------------------------------------------------------------------
template <int LAYER, bool ALIN, bool ALOUT>
__global__ __launch_bounds__(1024, 4) void k_mix(const float* __restrict__ pin,
                                                 const float* __restrict__ costs,
                                                 float* __restrict__ pout,
                                                 const float* __restrict__ gamma,
                                                 const float* __restrict__ beta,
                                                 double* __restrict__ scal) {
    __shared__ float4 tile[1024];     // 16 KB
    __shared__ double dpart[16];
    const unsigned lq = threadIdx.x;               // local quad 0..1023
    const unsigned db = dbswz(blockIdx.x);
    const unsigned i4 = db * 1024u + lq;           // global quad < 2^18
    float s = 0.1f * sinf(beta[LAYER]);
    float prevscale = (LAYER == 0) ? 1.0f : (float)(1.0 / sqrt(scal[LAYER - 1]));

    auto ld4 = [&](unsigned j4) -> float4 {
        if (ALIN) return ((const float4*)pin)[j4];
        float4 a;
        a.x = pin[4u * j4 + 0]; a.y = pin[4u * j4 + 1];
        a.z = pin[4u * j4 + 2]; a.w = pin[4u * j4 + 3];
        return a;
    };

    float4 own = ld4(i4);
    tile[lq] = own;

    // 8 far gathers (p = 19..12), single batch for max MLP
    float4 gv[8];
    #pragma unroll
    for (int p = 19; p >= 12; --p) gv[19 - p] = ld4(i4 ^ (1u << (p - 2)));

    __syncthreads();

    float4 nb = make_float4(0.f, 0.f, 0.f, 0.f);
    #pragma unroll
    for (int u = 0; u < 8; ++u) {      // p = 19..12 descending
        nb.x += gv[u].x; nb.y += gv[u].y; nb.z += gv[u].z; nb.w += gv[u].w;
    }
    #pragma unroll
    for (int p = 11; p >= 2; --p) {    // local flips from LDS
        float4 v = tile[lq ^ (1u << (p - 2))];
        nb.x += v.x; nb.y += v.y; nb.z += v.z; nb.w += v.w;
    }
    // p = 1: element e gets own element e^2
    nb.x += own.z; nb.y += own.w; nb.z += own.x; nb.w += own.y;
    // p = 0: element e gets own element e^1
    nb.x += own.y; nb.y += own.x; nb.z += own.w; nb.w += own.z;

    float4 m;
    m.x = prevscale * fmaf(s, nb.x, own.x);
    m.y = prevscale * fmaf(s, nb.y, own.y);
    m.z = prevscale * fmaf(s, nb.z, own.z);
    m.w = prevscale * fmaf(s, nb.w, own.w);

    float4 o;
    if (LAYER < 2) {
        float gn = gamma[LAYER + 1];
        float4 c = ((const float4*)costs)[i4];
        o.x = m.x * cosf(gn * c.x);
        o.y = m.y * cosf(gn * c.y);
        o.z = m.z * cosf(gn * c.z);
        o.w = m.w * cosf(gn * c.w);
    } else {
        o = m;
    }
    if (ALOUT) {
        ((float4*)pout)[i4] = o;
    } else {
        pout[4u * i4 + 0] = o.x; pout[4u * i4 + 1] = o.y;
        pout[4u * i4 + 2] = o.z; pout[4u * i4 + 3] = o.w;
    }

    double ss = (double)m.x * m.x + (double)m.y * m.y +
                (double)m.z * m.z + (double)m.w * m.w;
    #pragma unroll
    for (int off = 32; off > 0; off >>= 1) ss += __shfl_down(ss, off);
    int wid = threadIdx.x >> 6;
    if ((threadIdx.x & 63) == 0) dpart[wid] = ss;
    __syncthreads();
    if (threadIdx.x == 0) {
        double tt = 0.0;
        #pragma unroll
        for (int w = 0; w < 16; ++w) tt += dpart[w];
        atomicAdd(&scal[LAYER], tt);
    }
}

// ---------------------------------------------------------------------------
// Fused probs + top-k stage 1 + (last block) stage 2 merge & readout.
// Identical logic to the validated R4 version; reads its 4096-element segment
// at dbswz(blockIdx) so it consumes mix2's output from the same XCD's L2.
// ---------------------------------------------------------------------------
template <bool ALIN>
__global__ __launch_bounds__(256) void k_ptop(const float* __restrict__ A,
                                              const double* __restrict__ scal2,
                                              const float* __restrict__ costs,
                                              float* __restrict__ out,
                                              unsigned long long* __restrict__ cand,
                                              unsigned* __restrict__ ctr) {
    __shared__ unsigned long long warr[4];
    __shared__ int lastblk;
    __shared__ unsigned topi[TOPK];
    __shared__ float topc[TOPK];
    const int tid = threadIdx.x;
    float* probs_out = out + 21;
    unsigned b4 = dbswz(blockIdx.x) * 1024u;   // float4 base
    float scale = (float)(1.0 / sqrt(*scal2));

    unsigned long long k[16];
    #pragma unroll
    for (int u = 0; u < 4; ++u) {
        unsigned j4 = b4 + (unsigned)tid + 256u * u;
        float4 v;
        if (ALIN) v = ((const float4*)A)[j4];
        else {
            v.x = A[4u * j4 + 0]; v.y = A[4u * j4 + 1];
            v.z = A[4u * j4 + 2]; v.w = A[4u * j4 + 3];
        }
        float4 p;
        p.x = v.x * scale; p.x *= p.x;
        p.y = v.y * scale; p.y *= p.y;
        p.z = v.z * scale; p.z *= p.z;
        p.w = v.w * scale; p.w *= p.w;
        unsigned e0 = 4u * j4;
        probs_out[e0 + 0] = p.x; probs_out[e0 + 1] = p.y;
        probs_out[e0 + 2] = p.z; probs_out[e0 + 3] = p.w;
        k[4 * u + 0] = ((unsigned long long)__float_as_uint(p.x) << 32) | (unsigned long long)(0xFFFFFFFFu - (e0 + 0));
        k[4 * u + 1] = ((unsigned long long)__float_as_uint(p.y) << 32) | (unsigned long long)(0xFFFFFFFFu - (e0 + 1));
        k[4 * u + 2] = ((unsigned long long)__float_as_uint(p.z) << 32) | (unsigned long long)(0xFFFFFFFFu - (e0 + 2));
        k[4 * u + 3] = ((unsigned long long)__float_as_uint(p.w) << 32) | (unsigned long long)(0xFFFFFFFFu - (e0 + 3));
    }

    for (int r = 0; r < TOPK; ++r) {
        unsigned long long loc = 0ull;
        #pragma unroll
        for (int j = 0; j < 16; ++j) if (k[j] > loc) loc = k[j];
        #pragma unroll
        for (int off = 32; off > 0; off >>= 1) {
            unsigned long long o = __shfl_down(loc, off);
            if (o > loc) loc = o;
        }
        if ((tid & 63) == 0) warr[tid >> 6] = loc;
        __syncthreads();
        unsigned long long win = warr[0];
        if (warr[1] > win) win = warr[1];
        if (warr[2] > win) win = warr[2];
        if (warr[3] > win) win = warr[3];
        __syncthreads();
        #pragma unroll
        for (int j = 0; j < 16; ++j) if (k[j] == win) k[j] = 0ull;
        if (tid == 0) cand[blockIdx.x * TOPK + r] = win;
    }

    // ---- last-block ticket ----
    __threadfence();
    if (tid == 0) {
        unsigned old = atomicAdd(ctr, 1u);
        lastblk = (old == NB1 - 1) ? 1 : 0;
    }
    __syncthreads();
    if (!lastblk) return;
    __threadfence();

    // ---- stage 2: merge NCAND candidates with this one block ----
    unsigned long long c2[TOPK];
    #pragma unroll
    for (int u = 0; u < TOPK; ++u) c2[u] = cand[tid + 256 * u];

    for (int r = 0; r < TOPK; ++r) {
        unsigned long long loc = 0ull;
        #pragma unroll
        for (int u = 0; u < TOPK; ++u) if (c2[u] > loc) loc = c2[u];
        #pragma unroll
        for (int off = 32; off > 0; off >>= 1) {
            unsigned long long o = __shfl_down(loc, off);
            if (o > loc) loc = o;
        }
        if ((tid & 63) == 0) warr[tid >> 6] = loc;
        __syncthreads();
        unsigned long long win = warr[0];
        if (warr[1] > win) win = warr[1];
        if (warr[2] > win) win = warr[2];
        if (warr[3] > win) win = warr[3];
        __syncthreads();
        #pragma unroll
        for (int u = 0; u < TOPK; ++u) if (c2[u] == win) c2[u] = 0ull;
        if (tid == 0) topi[r] = 0xFFFFFFFFu - (unsigned)(win & 0xFFFFFFFFull);
        __syncthreads();
    }

    const unsigned S = NSTATES;
    if (tid < TOPK * NV) {
        int kk = tid / NV, vv = tid % NV;
        out[21 + S + (unsigned)tid] = (float)((topi[kk] >> (NV - 1 - vv)) & 1u);
    }
    if (tid < TOPK) {
        float c = costs[topi[tid]];
        topc[tid] = c;
        out[21 + S + TOPK * NV + (unsigned)tid] = c;
    }
    __syncthreads();
    if (tid == 0) {
        int best = 0;
        for (int kk = 1; kk < TOPK; ++kk)
            if (topc[kk] < topc[best]) best = kk;
        unsigned gi = topi[best];
        for (int vv = 0; vv < NV; ++vv)
            out[vv] = (float)((gi >> (NV - 1 - vv)) & 1u);
        out[NV] = topc[best];
    }
}

extern "C" void kernel_launch(void* const* d_in, const int* in_sizes, int n_in,
                              void* d_out_, int out_size, void* d_ws, size_t ws_size,
                              hipStream_t stream) {
    (void)in_sizes; (void)n_in; (void)out_size;
    const float* C     = (const float*)d_in[0];
    const float* beta  = (const float*)d_in[1];
    const float* gamma = (const float*)d_in[2];
    float* out = (float*)d_out_;
    char* ws = (char*)d_ws;
    const size_t S4 = (size_t)NSTATES * sizeof(float);

    double* scal = (double*)ws;                                   // 8 doubles
    unsigned* ctr = (unsigned*)(ws + 64);
    unsigned long long* cand = (unsigned long long*)(ws + 1024);  // 20 KB
    float* costs = (float*)(ws + 32768);
    float* A     = (float*)(ws + 32768 + S4);                     // ph0 / pm2
    const size_t need_full = 32768 + 3 * S4;
    bool wsbig = (ws_size >= need_full);
    float* B = wsbig ? (float*)(ws + 32768 + 2 * S4) : (out + 21); // pm1 / m2

    // costs + layer-0 phase array (A = ph0); 256 blocks, aligned ownership
    k_costs<<<256, 512, 0, stream>>>(C, costs, A, gamma, scal, ctr);

    // mix0: A(ph0) -> B(pm1);  mix1: B(pm1) -> A(pm2);  mix2: A(pm2) -> B(m2)
    if (wsbig) {
        k_mix<0, true, true ><<<256, 1024, 0, stream>>>(A, costs, B, gamma, beta, scal);
        k_mix<1, true, true ><<<256, 1024, 0, stream>>>(B, costs, A, gamma, beta, scal);
        k_mix<2, true, true ><<<256, 1024, 0, stream>>>(A, costs, B, gamma, beta, scal);
        k_ptop<true ><<<NB1, 256, 0, stream>>>(B, scal + 2, costs, out, cand, ctr);
    } else {
        k_mix<0, true, false><<<256, 1024, 0, stream>>>(A, costs, B, gamma, beta, scal);
        k_mix<1, false, true><<<256, 1024, 0, stream>>>(B, costs, A, gamma, beta, scal);
        k_mix<2, true, false><<<256, 1024, 0, stream>>>(A, costs, B, gamma, beta, scal);
        k_ptop<false><<<NB1, 256, 0, stream>>>(B, scal + 2, costs, out, cand, ctr);
    }
}